// Round 1
// baseline (150.089 us; speedup 1.0000x reference)
//
#include <hip/hip_runtime.h>
#include <hip/hip_bf16.h>

// Problem constants
#define BB 16384
#define LL 9
#define DD 32
#define CR 128

// ws layout (floats): A1[32][128], A2[32][128], WK[17][128]
// A1 = Wi@W1, A2 = Wj@W1, WK[k] = (r_k + bi + bj)@W1 + b1 with r_k from relpos row (i-j=k-8)

__global__ void precomp_kernel(const float* __restrict__ relpos,
                               const float* __restrict__ Wi, const float* __restrict__ bi,
                               const float* __restrict__ Wj, const float* __restrict__ bj,
                               const float* __restrict__ Wr, const float* __restrict__ br,
                               const float* __restrict__ W1, const float* __restrict__ b1,
                               float* __restrict__ ws)
{
    __shared__ float rv[DD];
    float* A1 = ws;
    float* A2 = ws + DD * CR;
    float* WK = ws + 2 * DD * CR;

    const int c = threadIdx.x;   // 0..127
    const int blk = blockIdx.x;  // 0..80

    if (blk < 32) {
        const int d = blk;
        float s = 0.f;
        #pragma unroll
        for (int e = 0; e < DD; ++e) s = fmaf(Wi[d * DD + e], W1[e * CR + c], s);
        A1[d * CR + c] = s;
    } else if (blk < 64) {
        const int d = blk - 32;
        float s = 0.f;
        #pragma unroll
        for (int e = 0; e < DD; ++e) s = fmaf(Wj[d * DD + e], W1[e * CR + c], s);
        A2[d * CR + c] = s;
    } else {
        const int k = blk - 64;       // 0..16, dk = k-8 = i-j
        const int dk = k - 8;
        const int i = dk > 0 ? dk : 0;
        const int j = i - dk;
        if (c < DD) {
            float s = bi[c] + bj[c] + br[c];
            #pragma unroll
            for (int d = 0; d < DD; ++d)
                s = fmaf(relpos[(i * LL + j) * DD + d], Wr[d * DD + c], s);
            rv[c] = s;
        }
        __syncthreads();
        float s = b1[c];
        #pragma unroll
        for (int e = 0; e < DD; ++e) s = fmaf(rv[e], W1[e * CR + c], s);
        WK[k * CR + c] = s;
    }
}

__global__ __launch_bounds__(256, 2) void outersum_main(
    const float* __restrict__ seq,
    const float* __restrict__ ws,
    const float* __restrict__ W2,
    const float* __restrict__ b2,
    float* __restrict__ out)
{
    const float* gA1 = ws;
    const float* gA2 = ws + DD * CR;
    const float* gWK = ws + 2 * DD * CR;

    const int lane = threadIdx.x & 63;
    const int wave = blockIdx.x * (blockDim.x >> 6) + (threadIdx.x >> 6);
    const int nw = (gridDim.x * blockDim.x) >> 6;
    const int c0 = lane;
    const int c1 = lane + 64;

    // Persistent per-wave state: A1/A2 columns for this lane's two channels.
    float a1[DD][2], a2[DD][2];
    #pragma unroll
    for (int d = 0; d < DD; ++d) {
        a1[d][0] = gA1[d * CR + c0];
        a1[d][1] = gA1[d * CR + c1];
        a2[d][0] = gA2[d * CR + c0];
        a2[d][1] = gA2[d * CR + c1];
    }
    float wk[17][2];
    #pragma unroll
    for (int k = 0; k < 17; ++k) {
        wk[k][0] = gWK[k * CR + c0];
        wk[k][1] = gWK[k * CR + c1];
    }
    const float w200 = W2[c0 * 2 + 0], w201 = W2[c0 * 2 + 1];
    const float w210 = W2[c1 * 2 + 0], w211 = W2[c1 * 2 + 1];
    const float bias0 = 81.f * b2[0], bias1 = 81.f * b2[1];

    for (int b = wave; b < BB; b += nw) {
        const int bu = __builtin_amdgcn_readfirstlane(b);
        const float* __restrict__ sp = seq + (long)bu * (LL * DD);

        float U[LL][2], V[LL][2];
        #pragma unroll
        for (int i = 0; i < LL; ++i) {
            float u0 = 0.f, u1 = 0.f, v0 = 0.f, v1 = 0.f;
            #pragma unroll
            for (int d = 0; d < DD; ++d) {
                const float s = sp[i * DD + d];  // wave-uniform
                u0 = fmaf(s, a1[d][0], u0);
                u1 = fmaf(s, a1[d][1], u1);
                v0 = fmaf(s, a2[d][0], v0);
                v1 = fmaf(s, a2[d][1], v1);
            }
            U[i][0] = u0; U[i][1] = u1;
            V[i][0] = v0; V[i][1] = v1;
        }

        float acc0 = 0.f, acc1 = 0.f;
        #pragma unroll
        for (int i = 0; i < LL; ++i) {
            #pragma unroll
            for (int j = 0; j < LL; ++j) {
                const int k = i - j + 8;
                float t0 = U[i][0] + V[j][0] + wk[k][0];
                float t1 = U[i][1] + V[j][1] + wk[k][1];
                t0 = fmaxf(t0, 0.f);
                t1 = fmaxf(t1, 0.f);
                acc0 = fmaf(t0, w200, fmaf(t1, w210, acc0));
                acc1 = fmaf(t0, w201, fmaf(t1, w211, acc1));
            }
        }

        // wave-level sum across 64 lanes
        #pragma unroll
        for (int off = 32; off; off >>= 1) {
            acc0 += __shfl_xor(acc0, off, 64);
            acc1 += __shfl_xor(acc1, off, 64);
        }
        if (lane == 0) {
            out[bu * 2 + 0] = acc0 + bias0;
            out[bu * 2 + 1] = acc1 + bias1;
        }
    }
}

extern "C" void kernel_launch(void* const* d_in, const int* in_sizes, int n_in,
                              void* d_out, int out_size, void* d_ws, size_t ws_size,
                              hipStream_t stream)
{
    const float* seq    = (const float*)d_in[0];
    const float* relpos = (const float*)d_in[1];
    const float* Wi     = (const float*)d_in[2];
    const float* bi     = (const float*)d_in[3];
    const float* Wj     = (const float*)d_in[4];
    const float* bj     = (const float*)d_in[5];
    const float* Wr     = (const float*)d_in[6];
    const float* br     = (const float*)d_in[7];
    const float* W1     = (const float*)d_in[8];
    const float* b1     = (const float*)d_in[9];
    const float* W2     = (const float*)d_in[10];
    const float* b2     = (const float*)d_in[11];
    float* out = (float*)d_out;
    float* ws  = (float*)d_ws;

    precomp_kernel<<<81, 128, 0, stream>>>(relpos, Wi, bi, Wj, bj, Wr, br, W1, b1, ws);

    // 512 blocks x 4 waves = 2048 waves; 8 batches per wave.
    outersum_main<<<512, 256, 0, stream>>>(seq, ws, W2, b2, out);
}